// Round 6
// baseline (733.987 us; speedup 1.0000x reference)
//
#include <hip/hip_runtime.h>
#include <hip/hip_bf16.h>

typedef unsigned short u16;
typedef unsigned int u32;
typedef unsigned long long u64;
typedef __attribute__((ext_vector_type(8))) short bf16x8;
typedef __attribute__((ext_vector_type(4))) float f32x4;
typedef __attribute__((ext_vector_type(2))) float f32x2;

#define NROWS 32768
#define KCODES 4096
#define DDIM 256
#define HW 1024
#define ZSTRIDE_B 262144ULL

// output element offsets (fp32 elements)
#define OFF_ZQ   0ULL
#define OFF_LOSS 8388608ULL
#define OFF_PERP 8388609ULL
#define OFF_OH   8388610ULL
#define OFF_IDX  142606338ULL
#define OFF_DIST 142639106ULL

// bf16 temporaries stashed inside the onehot output region
#define T_ZH 16777280ULL     // bf16 [32768][256] as u16
#define T_EH 25165888ULL     // bf16 [4096][256] as u16

// ws byte offsets
#define WS_IDX    0          // u32[32768]
#define WS_COUNTS 131072     // u32[4096]
#define WS_EN2    147456     // f32[4096]
#define WS_ZN2    163840     // f32[32768]
#define WS_PART   294912     // f32[128]
#define WS_BDIST  295424     // f32[32768]
#define WS_BMIN   524288     // f32[32768][32][2]  (8 MB)

static __device__ __forceinline__ void nt_store_f2(float* p, float a, float b) {
    f32x2 v = {a, b};
    __builtin_nontemporal_store(v, (f32x2*)p);
}
static __device__ __forceinline__ void nt_store_f(float* p, float v) {
    __builtin_nontemporal_store(v, p);
}

// emb row -> en2 (same reduce tree as before) + bf16-hi cast, fused
__global__ __launch_bounds__(64) void k_prep_e_en2(const float* __restrict__ emb,
                                                   float* __restrict__ en2,
                                                   u16* __restrict__ Ehh) {
    int k = blockIdx.x;
    int l = threadIdx.x;
    float4 v = *(const float4*)(emb + (size_t)k * DDIM + l * 4);
    float s = v.x * v.x + v.y * v.y + v.z * v.z + v.w * v.w;
    #pragma unroll
    for (int m = 32; m; m >>= 1) s += __shfl_xor(s, m);
    if (l == 0) en2[k] = s;
    float vv[4] = {v.x, v.y, v.z, v.w};
    u16 ho[4];
    #pragma unroll
    for (int j = 0; j < 4; ++j) {
        __hip_bfloat16 hb = __float2bfloat16(vv[j]);
        ho[j] = *(u16*)&hb;
    }
    *(ushort4*)(Ehh + (size_t)k * DDIM + l * 4) = make_ushort4(ho[0], ho[1], ho[2], ho[3]);
}

// one z pass: transpose -> Zhh bf16(hi)  AND  zn2 (d-ascending fmaf, exact
// same summation order as the reference-path k_zn2 of prior passing rounds)
__global__ __launch_bounds__(256) void k_prep_z(const float* __restrict__ z,
                                                u16* __restrict__ Zhh,
                                                float* __restrict__ zn2) {
    __shared__ float t[32][132];
    const int tid = threadIdx.x;
    const int h0 = blockIdx.x * 128, b = blockIdx.y;
    const float* zp = z + (size_t)b * ZSTRIDE_B;
    float zacc = 0.f;
    for (int slab = 0; slab < 8; ++slab) {
        const int d0 = slab * 32;
        __syncthreads();
        {
            int hq = (tid & 31) << 2;
            int dr = tid >> 5;
            #pragma unroll
            for (int p = 0; p < 4; ++p) {
                int d = p * 8 + dr;
                float4 v = *(const float4*)(zp + (size_t)(d0 + d) * HW + h0 + hq);
                *(float4*)&t[d][hq] = v;
            }
        }
        __syncthreads();
        if (tid < 128) {
            #pragma unroll 8
            for (int d = 0; d < 32; ++d) {
                float v = t[d][tid];
                zacc = fmaf(v, v, zacc);
            }
        }
        {
            int nr = tid >> 1;
            int half = tid & 1;
            int n = b * HW + h0 + nr;
            u16 hv[16];
            #pragma unroll
            for (int i = 0; i < 16; ++i) {
                float v = t[half * 16 + i][nr];
                __hip_bfloat16 hb = __float2bfloat16(v);
                hv[i] = *(u16*)&hb;
            }
            u16* dst = Zhh + (size_t)n * DDIM + d0 + half * 16;
            #pragma unroll
            for (int q = 0; q < 4; ++q)
                *(ushort4*)(dst + q * 4) = *(ushort4*)&hv[q * 4];
        }
    }
    if (tid < 128) zn2[b * HW + h0 + tid] = zacc;
}

// hi*hi bf16 MFMA distance GEMM: 128x128 tile, BK=64, K=256.
// Epilogue stages C through LDS for contiguous 512B nontemporal row writes.
__global__ __launch_bounds__(256) void k_dist_mfma(
    const u16* __restrict__ Zhh, const u16* __restrict__ Ehh,
    const float* __restrict__ zn2, const float* __restrict__ en2,
    float* __restrict__ dist, float* __restrict__ bmin)
{
    __shared__ __align__(16) u16 smem[17408];     // 34 KB: As|Bs, aliased Ct
    u16* As = smem;                               // [128][64] bf16, swizzled
    u16* Bs = smem + 8192;
    float* Ct = (float*)smem;                     // [32][132] fp32 epilogue

    const int tid = threadIdx.x;
    const int w = tid >> 6, l = tid & 63;
    const int n0 = blockIdx.x * 128, k0 = blockIdx.y * 128;
    const int kb = blockIdx.y;
    const int wr = w >> 1, wc = w & 1;

    int goff[4], loff[4];
    #pragma unroll
    for (int it = 0; it < 4; ++it) {
        int o = (it << 12) + (w << 10) + (l << 4);
        int r = o >> 7;
        int c16 = (o >> 4) & 7;
        int gs = c16 ^ (r & 7);
        goff[it] = r * DDIM + gs * 8;
        loff[it] = (it << 11) + (w << 9);
    }

    f32x4 acc[4][4];
    #pragma unroll
    for (int m = 0; m < 4; ++m)
        #pragma unroll
        for (int n = 0; n < 4; ++n)
            acc[m][n] = (f32x4){0.f, 0.f, 0.f, 0.f};

    const int lr = l & 15, ks = l >> 4;
    const int ra = wr * 64 + lr, rb = wc * 64 + lr;

    const u16* Ap = Zhh + (size_t)n0 * DDIM;
    const u16* Bp = Ehh + (size_t)k0 * DDIM;
    for (int st = 0; st < 4; ++st) {
        const int d0 = st * 64;
        #pragma unroll
        for (int it = 0; it < 4; ++it) {
            __builtin_amdgcn_global_load_lds(
                (const __attribute__((address_space(1))) void*)(Ap + d0 + goff[it]),
                (__attribute__((address_space(3))) void*)(As + loff[it]), 16, 0, 0);
            __builtin_amdgcn_global_load_lds(
                (const __attribute__((address_space(1))) void*)(Bp + d0 + goff[it]),
                (__attribute__((address_space(3))) void*)(Bs + loff[it]), 16, 0, 0);
        }
        __syncthreads();
        #pragma unroll
        for (int kk = 0; kk < 2; ++kk) {
            bf16x8 af[4], bfr[4];
            #pragma unroll
            for (int m = 0; m < 4; ++m) {
                int rr = ra + m * 16;
                af[m] = *(const bf16x8*)&As[rr * 64 + ((kk * 4 + ks) ^ (rr & 7)) * 8];
            }
            #pragma unroll
            for (int n = 0; n < 4; ++n) {
                int rr = rb + n * 16;
                bfr[n] = *(const bf16x8*)&Bs[rr * 64 + ((kk * 4 + ks) ^ (rr & 7)) * 8];
            }
            #pragma unroll
            for (int m = 0; m < 4; ++m)
                #pragma unroll
                for (int n = 0; n < 4; ++n)
                    acc[m][n] = __builtin_amdgcn_mfma_f32_16x16x32_bf16(
                        af[m], bfr[n], acc[m][n], 0, 0, 0);
        }
        __syncthreads();
    }

    float ev[4];
    #pragma unroll
    for (int n = 0; n < 4; ++n) ev[n] = en2[k0 + wc * 64 + n * 16 + lr];

    #pragma unroll
    for (int m = 0; m < 4; ++m) {
        // compute dv (bit-identical path), stage into Ct, and emit bmin
        #pragma unroll
        for (int r = 0; r < 4; ++r) {
            int row = n0 + wr * 64 + m * 16 + ks * 4 + r;
            float t = zn2[row];
            int ridx = wr * 16 + ks * 4 + r;
            float rm = 3.4e38f;
            #pragma unroll
            for (int n = 0; n < 4; ++n) {
                float s  = __fadd_rn(t, ev[n]);
                float m2 = __fmul_rn(2.0f, acc[m][n][r]);
                float dv = __fsub_rn(s, m2);
                Ct[ridx * 132 + wc * 64 + n * 16 + lr] = dv;
                rm = fminf(rm, dv);
            }
            #pragma unroll
            for (int msk = 1; msk < 16; msk <<= 1)
                rm = fminf(rm, __shfl_xor(rm, msk));
            if (lr == 0)
                bmin[((size_t)row * 32 + kb) * 2 + wc] = rm;
        }
        __syncthreads();
        // each wave writes 8 full 512B row segments (64 lanes x float2, NT)
        #pragma unroll
        for (int rr = 0; rr < 8; ++rr) {
            int rid = w * 8 + rr;
            int grow = n0 + m * 16 + (rid >> 4) * 64 + (rid & 15);
            float a = Ct[rid * 132 + l * 2];
            float bvv = Ct[rid * 132 + l * 2 + 1];
            nt_store_f2(dist + (size_t)grow * KCODES + k0 + l * 2, a, bvv);
        }
        __syncthreads();
    }
}

// per-row: block-minima -> qualifying tiles -> exact fp32 re-rank (+ bdist out)
__global__ __launch_bounds__(256) void k_select(
    const float* __restrict__ dist, const float* __restrict__ z,
    const float* __restrict__ emb, const float* __restrict__ zn2,
    const float* __restrict__ en2, const float* __restrict__ bmin,
    u32* __restrict__ idxarr, float* __restrict__ bdist)
{
    const int l = threadIdx.x & 63;
    const int row = blockIdx.x * 4 + (threadIdx.x >> 6);
    float bm = bmin[(size_t)row * 64 + l];   // [kb][wc]
    float mn = bm;
    #pragma unroll
    for (int m = 1; m < 64; m <<= 1) mn = fminf(mn, __shfl_xor(mn, m));
    const float thr = mn + 1e-3f;
    u64 qual = __ballot(bm <= thr);

    const int b = row >> 10, hw = row & 1023;
    const float* zp = z + (size_t)b * ZSTRIDE_B + hw;
    float z0 = zp[(size_t)(l * 4 + 0) * HW];
    float z1 = zp[(size_t)(l * 4 + 1) * HW];
    float z2 = zp[(size_t)(l * 4 + 2) * HW];
    float z3 = zp[(size_t)(l * 4 + 3) * HW];
    const float zr = zn2[row];

    u64 best = ~0ull;
    int prev_kb = -1;
    u64 qq = qual;
    while (qq) {
        int bit = __ffsll(qq) - 1; qq &= qq - 1;
        int kb = bit >> 1;
        if (kb == prev_kb) continue;
        prev_kb = kb;
        const float* dr = dist + (size_t)row * KCODES + kb * 128;
        float2 d2 = *(const float2*)(dr + l * 2);
        u64 c0 = __ballot(d2.x <= thr);
        u64 c1 = __ballot(d2.y <= thr);
        u64 any = c0 | c1;
        while (any) {
            int src = __ffsll(any) - 1; any &= any - 1;
            #pragma unroll
            for (int e = 0; e < 2; ++e) {
                u64 msk = e ? c1 : c0;
                if (!((msk >> src) & 1)) continue;
                int k = kb * 128 + src * 2 + e;
                float4 e4 = *(const float4*)(emb + (size_t)k * DDIM + l * 4);
                float p = 0.f;
                p = fmaf(z0, e4.x, p);
                p = fmaf(z1, e4.y, p);
                p = fmaf(z2, e4.z, p);
                p = fmaf(z3, e4.w, p);
                #pragma unroll
                for (int m = 1; m < 64; m <<= 1) p += __shfl_xor(p, m);
                float dh = __fsub_rn(__fadd_rn(zr, en2[k]), __fmul_rn(2.0f, p));
                u32 ub = __float_as_uint(dh);
                ub = (ub & 0x80000000u) ? ~ub : (ub | 0x80000000u);
                u64 cand = ((u64)ub << 32) | (u32)k;
                best = cand < best ? cand : best;
            }
        }
    }
    if (l == 0) {
        idxarr[row] = (u32)(best & 0xffffffffu);
        u32 ub = (u32)(best >> 32);
        u32 fb = (ub & 0x80000000u) ? (ub & 0x7fffffffu) : ~ub;
        bdist[row] = __uint_as_float(fb);
    }
}

// zq gather + idx + counts + loss partials from bdist (no z read)
__global__ __launch_bounds__(256) void k_zq(const float* __restrict__ emb,
                                            const u32* __restrict__ idxarr,
                                            const float* __restrict__ bdist,
                                            unsigned* __restrict__ counts,
                                            float* __restrict__ out,
                                            float* __restrict__ partials) {
    int n = blockIdx.x * 256 + threadIdx.x;
    unsigned idx = idxarr[n];
    out[OFF_IDX + n] = (float)idx;
    atomicAdd(counts + idx, 1u);
    int b = n >> 10, hw = n & 1023;
    const float* ep = emb + (size_t)idx * DDIM;
    float* oq = out + OFF_ZQ + (size_t)b * ZSTRIDE_B + hw;
    #pragma unroll 2
    for (int d = 0; d < DDIM; d += 4) {
        float4 e4 = *(const float4*)(ep + d);
        nt_store_f(oq + (size_t)(d + 0) * HW, e4.x);
        nt_store_f(oq + (size_t)(d + 1) * HW, e4.y);
        nt_store_f(oq + (size_t)(d + 2) * HW, e4.z);
        nt_store_f(oq + (size_t)(d + 3) * HW, e4.w);
    }
    __shared__ float red[256];
    red[threadIdx.x] = bdist[n];
    __syncthreads();
    for (int st = 128; st > 0; st >>= 1) {
        if (threadIdx.x < st) red[threadIdx.x] += red[threadIdx.x + st];
        __syncthreads();
    }
    if (threadIdx.x == 0) partials[blockIdx.x] = red[0];
}

// onehot rows (zeros + single 1.0), wave per row, 32B/lane NT writes;
// block 0 also finalizes loss/perplexity.
__global__ __launch_bounds__(256) void k_onehot(const u32* __restrict__ idxarr,
                                                const unsigned* __restrict__ counts,
                                                const float* __restrict__ partials,
                                                float* __restrict__ out) {
    const int l = threadIdx.x & 63;
    const int n = blockIdx.x * 4 + (threadIdx.x >> 6);
    const int idx = (int)idxarr[n];
    float* base = out + OFF_OH + (size_t)n * KCODES;
    #pragma unroll
    for (int i = 0; i < 8; ++i) {
        int c0 = i * 512 + l * 8;
        #pragma unroll
        for (int q = 0; q < 4; ++q) {
            float a = (idx == c0 + 2 * q)     ? 1.0f : 0.0f;
            float bv = (idx == c0 + 2 * q + 1) ? 1.0f : 0.0f;
            nt_store_f2(base + c0 + 2 * q, a, bv);
        }
    }
    if (blockIdx.x == 0) {
        __shared__ float red[256];
        int t = threadIdx.x;
        red[t] = (t < 128) ? partials[t] : 0.f;
        __syncthreads();
        for (int st = 128; st > 0; st >>= 1) {
            if (t < st) red[t] += red[t + st];
            __syncthreads();
        }
        float loss = 1.25f * (red[0] / 8388608.0f);
        __syncthreads();
        float h = 0.f;
        for (int k = t; k < KCODES; k += 256) {
            float p = (float)counts[k] * (1.0f / 32768.0f);
            h -= p * logf(p + 1e-10f);
        }
        red[t] = h;
        __syncthreads();
        for (int st = 128; st > 0; st >>= 1) {
            if (t < st) red[t] += red[t + st];
            __syncthreads();
        }
        if (t == 0) {
            out[OFF_LOSS] = loss;
            out[OFF_PERP] = expf(red[0]);
        }
    }
}

extern "C" void kernel_launch(void* const* d_in, const int* in_sizes, int n_in,
                              void* d_out, int out_size, void* d_ws, size_t ws_size,
                              hipStream_t stream) {
    (void)in_sizes; (void)n_in; (void)out_size; (void)ws_size;
    const float* z = (const float*)d_in[0];
    const float* emb = (const float*)d_in[1];
    float* out = (float*)d_out;
    char* ws = (char*)d_ws;
    u32* idxarr = (u32*)(ws + WS_IDX);
    unsigned* counts = (unsigned*)(ws + WS_COUNTS);
    float* en2 = (float*)(ws + WS_EN2);
    float* zn2 = (float*)(ws + WS_ZN2);
    float* partials = (float*)(ws + WS_PART);
    float* bdist = (float*)(ws + WS_BDIST);
    float* bmin = (float*)(ws + WS_BMIN);

    u16* Zhh = (u16*)(out + T_ZH);
    u16* Ehh = (u16*)(out + T_EH);
    float* dist = out + OFF_DIST;

    (void)hipMemsetAsync(counts, 0, (size_t)KCODES * 4, stream);

    k_prep_z<<<dim3(8, 32), 256, 0, stream>>>(z, Zhh, zn2);
    k_prep_e_en2<<<KCODES, 64, 0, stream>>>(emb, en2, Ehh);
    k_dist_mfma<<<dim3(NROWS / 128, KCODES / 128), 256, 0, stream>>>(
        Zhh, Ehh, zn2, en2, dist, bmin);
    k_select<<<NROWS / 4, 256, 0, stream>>>(dist, z, emb, zn2, en2, bmin,
                                            idxarr, bdist);
    k_zq<<<NROWS / 256, 256, 0, stream>>>(emb, idxarr, bdist, counts, out, partials);
    k_onehot<<<NROWS / 4, 256, 0, stream>>>(idxarr, counts, partials, out);
}

// Round 7
// 554.552 us; speedup vs baseline: 1.3236x; 1.3236x over previous
//
#include <hip/hip_runtime.h>
#include <hip/hip_bf16.h>

typedef unsigned short u16;
typedef unsigned int u32;
typedef unsigned long long u64;
typedef __attribute__((ext_vector_type(8))) short bf16x8;
typedef __attribute__((ext_vector_type(4))) float f32x4;

#define NROWS 32768
#define KCODES 4096
#define DDIM 256
#define HW 1024
#define ZSTRIDE_B 262144ULL

// output element offsets (fp32 elements)
#define OFF_ZQ   0ULL
#define OFF_LOSS 8388608ULL
#define OFF_PERP 8388609ULL
#define OFF_OH   8388610ULL
#define OFF_IDX  142606338ULL
#define OFF_DIST 142639106ULL

// bf16 temporaries stashed inside the onehot output region
// (fully overwritten by k_onehot afterwards)
#define T_ZH 16777280ULL     // bf16 [32768][256] as u16
#define T_EH 25165888ULL     // bf16 [4096][256] as u16

// ws byte offsets
#define WS_IDX    0          // u32[32768]
#define WS_COUNTS 131072     // u32[4096]
#define WS_EN2    147456     // f32[4096]
#define WS_ZN2    163840     // f32[32768]
#define WS_PART   294912     // f32[128]
#define WS_BDIST  295424     // f32[32768]
#define WS_BMIN   524288     // f32[32768][32][2]  (8 MB)

// emb row -> en2 (same value path as before) + bf16-hi cast, fused
__global__ __launch_bounds__(64) void k_prep_e_en2(const float* __restrict__ emb,
                                                   float* __restrict__ en2,
                                                   u16* __restrict__ Ehh) {
    int k = blockIdx.x;
    int l = threadIdx.x;
    float4 v = *(const float4*)(emb + (size_t)k * DDIM + l * 4);
    float s = v.x * v.x + v.y * v.y + v.z * v.z + v.w * v.w;
    #pragma unroll
    for (int m = 32; m; m >>= 1) s += __shfl_xor(s, m);
    if (l == 0) en2[k] = s;
    float vv[4] = {v.x, v.y, v.z, v.w};
    u16 ho[4];
    #pragma unroll
    for (int j = 0; j < 4; ++j) {
        __hip_bfloat16 hb = __float2bfloat16(vv[j]);
        ho[j] = *(u16*)&hb;
    }
    *(ushort4*)(Ehh + (size_t)k * DDIM + l * 4) = make_ushort4(ho[0], ho[1], ho[2], ho[3]);
}

// zn2: EXACT same summation order as prior passing rounds (sequential fmaf)
__global__ __launch_bounds__(256) void k_zn2(const float* __restrict__ z,
                                             float* __restrict__ zn2) {
    int n = blockIdx.x * 256 + threadIdx.x;
    int b = n >> 10, hw = n & 1023;
    const float* zp = z + (size_t)b * ZSTRIDE_B + hw;
    float s = 0.f;
    #pragma unroll 8
    for (int d = 0; d < DDIM; ++d) {
        float v = zp[(size_t)d * HW];
        s = fmaf(v, v, s);
    }
    zn2[n] = s;
}

// transpose z (b,d,hw) -> Zh[n][d] bf16(hi); 128hw x 32d tile, float4 reads
__global__ __launch_bounds__(256) void k_prep_z(const float* __restrict__ z,
                                                u16* __restrict__ Zhh) {
    __shared__ float t[32][132];
    const int tid = threadIdx.x;
    const int h0 = blockIdx.x * 128, d0 = blockIdx.y * 32, b = blockIdx.z;
    const float* zp = z + (size_t)b * ZSTRIDE_B;
    {
        int hq = (tid & 31) << 2;
        int dr = tid >> 5;
        #pragma unroll
        for (int p = 0; p < 4; ++p) {
            int d = p * 8 + dr;
            float4 v = *(const float4*)(zp + (size_t)(d0 + d) * HW + h0 + hq);
            *(float4*)&t[d][hq] = v;
        }
    }
    __syncthreads();
    {
        int nr = tid >> 1;
        int half = tid & 1;
        int n = b * HW + h0 + nr;
        u16 hv[16];
        #pragma unroll
        for (int i = 0; i < 16; ++i) {
            float v = t[half * 16 + i][nr];
            __hip_bfloat16 hb = __float2bfloat16(v);
            hv[i] = *(u16*)&hb;
        }
        u16* dst = Zhh + (size_t)n * DDIM + d0 + half * 16;
        #pragma unroll
        for (int q = 0; q < 4; ++q)
            *(ushort4*)(dst + q * 4) = *(ushort4*)&hv[q * 4];
    }
}

// hi*hi bf16 MFMA distance GEMM: 128x128 tile, BK=64, K=256 (4 steps).
// Epilogue stages C through LDS (aliased over As/Bs) so each wave emits
// full 512B contiguous row segments with PLAIN stores (no NT).
__global__ __launch_bounds__(256) void k_dist_mfma(
    const u16* __restrict__ Zhh, const u16* __restrict__ Ehh,
    const float* __restrict__ zn2, const float* __restrict__ en2,
    float* __restrict__ dist, float* __restrict__ bmin)
{
    __shared__ __align__(16) u16 smem[16384];     // 32 KB: As|Bs, aliased Ct
    u16* As = smem;                               // [128][64] bf16, swizzled
    u16* Bs = smem + 8192;
    float* Ct = (float*)smem;                     // [32][132] fp32 epilogue

    const int tid = threadIdx.x;
    const int w = tid >> 6, l = tid & 63;
    const int n0 = blockIdx.x * 128, k0 = blockIdx.y * 128;
    const int kb = blockIdx.y;
    const int wr = w >> 1, wc = w & 1;

    int goff[4], loff[4];
    #pragma unroll
    for (int it = 0; it < 4; ++it) {
        int o = (it << 12) + (w << 10) + (l << 4);  // byte off in 16KB tile
        int r = o >> 7;                             // 128B rows
        int c16 = (o >> 4) & 7;                     // 16B slot
        int gs = c16 ^ (r & 7);                     // swizzled source slot
        goff[it] = r * DDIM + gs * 8;               // u16 elems
        loff[it] = (it << 11) + (w << 9);           // u16, wave-uniform
    }

    f32x4 acc[4][4];
    #pragma unroll
    for (int m = 0; m < 4; ++m)
        #pragma unroll
        for (int n = 0; n < 4; ++n)
            acc[m][n] = (f32x4){0.f, 0.f, 0.f, 0.f};

    const int lr = l & 15, ks = l >> 4;
    const int ra = wr * 64 + lr, rb = wc * 64 + lr;

    const u16* Ap = Zhh + (size_t)n0 * DDIM;
    const u16* Bp = Ehh + (size_t)k0 * DDIM;
    for (int st = 0; st < 4; ++st) {
        const int d0 = st * 64;
        #pragma unroll
        for (int it = 0; it < 4; ++it) {
            __builtin_amdgcn_global_load_lds(
                (const __attribute__((address_space(1))) void*)(Ap + d0 + goff[it]),
                (__attribute__((address_space(3))) void*)(As + loff[it]), 16, 0, 0);
            __builtin_amdgcn_global_load_lds(
                (const __attribute__((address_space(1))) void*)(Bp + d0 + goff[it]),
                (__attribute__((address_space(3))) void*)(Bs + loff[it]), 16, 0, 0);
        }
        __syncthreads();
        #pragma unroll
        for (int kk = 0; kk < 2; ++kk) {
            bf16x8 af[4], bfr[4];
            #pragma unroll
            for (int m = 0; m < 4; ++m) {
                int rr = ra + m * 16;
                af[m] = *(const bf16x8*)&As[rr * 64 + ((kk * 4 + ks) ^ (rr & 7)) * 8];
            }
            #pragma unroll
            for (int n = 0; n < 4; ++n) {
                int rr = rb + n * 16;
                bfr[n] = *(const bf16x8*)&Bs[rr * 64 + ((kk * 4 + ks) ^ (rr & 7)) * 8];
            }
            #pragma unroll
            for (int m = 0; m < 4; ++m)
                #pragma unroll
                for (int n = 0; n < 4; ++n)
                    acc[m][n] = __builtin_amdgcn_mfma_f32_16x16x32_bf16(
                        af[m], bfr[n], acc[m][n], 0, 0, 0);
        }
        __syncthreads();
    }

    float ev[4];
    #pragma unroll
    for (int n = 0; n < 4; ++n) ev[n] = en2[k0 + wc * 64 + n * 16 + lr];

    #pragma unroll
    for (int m = 0; m < 4; ++m) {
        // compute dv (bit-identical value path), stage into Ct, emit bmin
        #pragma unroll
        for (int r = 0; r < 4; ++r) {
            int row = n0 + wr * 64 + m * 16 + ks * 4 + r;
            float t = zn2[row];
            int ridx = wr * 16 + ks * 4 + r;
            float rm = 3.4e38f;
            #pragma unroll
            for (int n = 0; n < 4; ++n) {
                float s  = __fadd_rn(t, ev[n]);
                float m2 = __fmul_rn(2.0f, acc[m][n][r]);
                float dv = __fsub_rn(s, m2);
                Ct[ridx * 132 + wc * 64 + n * 16 + lr] = dv;
                rm = fminf(rm, dv);
            }
            #pragma unroll
            for (int msk = 1; msk < 16; msk <<= 1)
                rm = fminf(rm, __shfl_xor(rm, msk));
            if (lr == 0)
                bmin[((size_t)row * 32 + kb) * 2 + wc] = rm;
        }
        __syncthreads();
        // each wave writes 8 full 512B row segments (64 lanes x float2)
        #pragma unroll
        for (int rr = 0; rr < 8; ++rr) {
            int rid = w * 8 + rr;
            int grow = n0 + m * 16 + (rid >> 4) * 64 + (rid & 15);
            float a = Ct[rid * 132 + l * 2];
            float b = Ct[rid * 132 + l * 2 + 1];
            *(float2*)(dist + (size_t)grow * KCODES + k0 + l * 2) = make_float2(a, b);
        }
        __syncthreads();
    }
}

// per-row: block-minima -> qualifying tiles -> exact fp32 re-rank (+ bdist out)
__global__ __launch_bounds__(256) void k_select(
    const float* __restrict__ dist, const float* __restrict__ z,
    const float* __restrict__ emb, const float* __restrict__ zn2,
    const float* __restrict__ en2, const float* __restrict__ bmin,
    u32* __restrict__ idxarr, float* __restrict__ bdist)
{
    const int l = threadIdx.x & 63;
    const int row = blockIdx.x * 4 + (threadIdx.x >> 6);
    float bm = bmin[(size_t)row * 64 + l];   // [kb][wc]
    float mn = bm;
    #pragma unroll
    for (int m = 1; m < 64; m <<= 1) mn = fminf(mn, __shfl_xor(mn, m));
    const float thr = mn + 1e-3f;
    u64 qual = __ballot(bm <= thr);

    const int b = row >> 10, hw = row & 1023;
    const float* zp = z + (size_t)b * ZSTRIDE_B + hw;
    float z0 = zp[(size_t)(l * 4 + 0) * HW];
    float z1 = zp[(size_t)(l * 4 + 1) * HW];
    float z2 = zp[(size_t)(l * 4 + 2) * HW];
    float z3 = zp[(size_t)(l * 4 + 3) * HW];
    const float zr = zn2[row];

    u64 best = ~0ull;
    int prev_kb = -1;
    u64 qq = qual;
    while (qq) {
        int bit = __ffsll(qq) - 1; qq &= qq - 1;
        int kb = bit >> 1;
        if (kb == prev_kb) continue;
        prev_kb = kb;
        const float* dr = dist + (size_t)row * KCODES + kb * 128;
        float2 d2 = *(const float2*)(dr + l * 2);
        u64 c0 = __ballot(d2.x <= thr);
        u64 c1 = __ballot(d2.y <= thr);
        u64 any = c0 | c1;
        while (any) {
            int src = __ffsll(any) - 1; any &= any - 1;
            #pragma unroll
            for (int e = 0; e < 2; ++e) {
                u64 msk = e ? c1 : c0;
                if (!((msk >> src) & 1)) continue;
                int k = kb * 128 + src * 2 + e;
                float4 e4 = *(const float4*)(emb + (size_t)k * DDIM + l * 4);
                float p = 0.f;
                p = fmaf(z0, e4.x, p);
                p = fmaf(z1, e4.y, p);
                p = fmaf(z2, e4.z, p);
                p = fmaf(z3, e4.w, p);
                #pragma unroll
                for (int m = 1; m < 64; m <<= 1) p += __shfl_xor(p, m);
                float dh = __fsub_rn(__fadd_rn(zr, en2[k]), __fmul_rn(2.0f, p));
                u32 ub = __float_as_uint(dh);
                ub = (ub & 0x80000000u) ? ~ub : (ub | 0x80000000u);
                u64 cand = ((u64)ub << 32) | (u32)k;
                best = cand < best ? cand : best;
            }
        }
    }
    if (l == 0) {
        idxarr[row] = (u32)(best & 0xffffffffu);
        u32 ub = (u32)(best >> 32);
        u32 fb = (ub & 0x80000000u) ? (ub & 0x7fffffffu) : ~ub;
        bdist[row] = __uint_as_float(fb);
    }
}

// zq gather + idx + counts + loss partials from bdist (no z read)
__global__ __launch_bounds__(256) void k_zq(const float* __restrict__ emb,
                                            const u32* __restrict__ idxarr,
                                            const float* __restrict__ bdist,
                                            unsigned* __restrict__ counts,
                                            float* __restrict__ out,
                                            float* __restrict__ partials) {
    int n = blockIdx.x * 256 + threadIdx.x;
    unsigned idx = idxarr[n];
    out[OFF_IDX + n] = (float)idx;
    atomicAdd(counts + idx, 1u);
    int b = n >> 10, hw = n & 1023;
    const float* ep = emb + (size_t)idx * DDIM;
    float* oq = out + OFF_ZQ + (size_t)b * ZSTRIDE_B + hw;
    #pragma unroll 2
    for (int d = 0; d < DDIM; d += 4) {
        float4 e4 = *(const float4*)(ep + d);
        oq[(size_t)(d + 0) * HW] = e4.x;
        oq[(size_t)(d + 1) * HW] = e4.y;
        oq[(size_t)(d + 2) * HW] = e4.z;
        oq[(size_t)(d + 3) * HW] = e4.w;
    }
    __shared__ float red[256];
    red[threadIdx.x] = bdist[n];
    __syncthreads();
    for (int st = 128; st > 0; st >>= 1) {
        if (threadIdx.x < st) red[threadIdx.x] += red[threadIdx.x + st];
        __syncthreads();
    }
    if (threadIdx.x == 0) partials[blockIdx.x] = red[0];
}

// onehot rows (zeros + single 1.0), one wave per row; block 0 also finalizes
__global__ __launch_bounds__(256) void k_onehot(const u32* __restrict__ idxarr,
                                                const unsigned* __restrict__ counts,
                                                const float* __restrict__ partials,
                                                float* __restrict__ out) {
    const int l = threadIdx.x & 63;
    const int n = blockIdx.x * 4 + (threadIdx.x >> 6);
    const int idx = (int)idxarr[n];
    float* base = out + OFF_OH + (size_t)n * KCODES;
    #pragma unroll
    for (int i = 0; i < 16; ++i) {
        int c0 = i * 256 + l * 4;
        float2 a, b2;
        a.x  = (idx == c0)     ? 1.0f : 0.0f;
        a.y  = (idx == c0 + 1) ? 1.0f : 0.0f;
        b2.x = (idx == c0 + 2) ? 1.0f : 0.0f;
        b2.y = (idx == c0 + 3) ? 1.0f : 0.0f;
        *(float2*)(base + c0) = a;
        *(float2*)(base + c0 + 2) = b2;
    }
    if (blockIdx.x == 0) {
        __shared__ float red[256];
        int t = threadIdx.x;
        red[t] = (t < 128) ? partials[t] : 0.f;
        __syncthreads();
        for (int st = 128; st > 0; st >>= 1) {
            if (t < st) red[t] += red[t + st];
            __syncthreads();
        }
        float loss = 1.25f * (red[0] / 8388608.0f);
        __syncthreads();
        float h = 0.f;
        for (int k = t; k < KCODES; k += 256) {
            float p = (float)counts[k] * (1.0f / 32768.0f);
            h -= p * logf(p + 1e-10f);
        }
        red[t] = h;
        __syncthreads();
        for (int st = 128; st > 0; st >>= 1) {
            if (t < st) red[t] += red[t + st];
            __syncthreads();
        }
        if (t == 0) {
            out[OFF_LOSS] = loss;
            out[OFF_PERP] = expf(red[0]);
        }
    }
}

extern "C" void kernel_launch(void* const* d_in, const int* in_sizes, int n_in,
                              void* d_out, int out_size, void* d_ws, size_t ws_size,
                              hipStream_t stream) {
    (void)in_sizes; (void)n_in; (void)out_size; (void)ws_size;
    const float* z = (const float*)d_in[0];
    const float* emb = (const float*)d_in[1];
    float* out = (float*)d_out;
    char* ws = (char*)d_ws;
    u32* idxarr = (u32*)(ws + WS_IDX);
    unsigned* counts = (unsigned*)(ws + WS_COUNTS);
    float* en2 = (float*)(ws + WS_EN2);
    float* zn2 = (float*)(ws + WS_ZN2);
    float* partials = (float*)(ws + WS_PART);
    float* bdist = (float*)(ws + WS_BDIST);
    float* bmin = (float*)(ws + WS_BMIN);

    u16* Zhh = (u16*)(out + T_ZH);
    u16* Ehh = (u16*)(out + T_EH);
    float* dist = out + OFF_DIST;

    (void)hipMemsetAsync(counts, 0, (size_t)KCODES * 4, stream);

    k_prep_z<<<dim3(8, 8, 32), 256, 0, stream>>>(z, Zhh);
    k_prep_e_en2<<<KCODES, 64, 0, stream>>>(emb, en2, Ehh);
    k_zn2<<<NROWS / 256, 256, 0, stream>>>(z, zn2);
    k_dist_mfma<<<dim3(NROWS / 128, KCODES / 128), 256, 0, stream>>>(
        Zhh, Ehh, zn2, en2, dist, bmin);
    k_select<<<NROWS / 4, 256, 0, stream>>>(dist, z, emb, zn2, en2, bmin,
                                            idxarr, bdist);
    k_zq<<<NROWS / 256, 256, 0, stream>>>(emb, idxarr, bdist, counts, out, partials);
    k_onehot<<<NROWS / 4, 256, 0, stream>>>(idxarr, counts, partials, out);
}